// Round 1
// baseline (118.707 us; speedup 1.0000x reference)
//
#include <hip/hip_runtime.h>

// SparseConv1x1: out[b,r,hw] = sum_{k in row r} values[k] * in[b,col[k],hw]
// Shapes: in [8,256,3136] f32, out [8,256,3136] f32, nnz ~6553 sorted by row (CSR order).
// HW=3136 divisible by 4 -> process float4 (4 pixels) per thread.

#define HWDIV4 784          // 3136/4
#define NPIX4  6272         // 8 * 784  (all batches, float4 units)
#define CH     256
#define NF     256

__global__ __launch_bounds__(256) void SparseConv1x1_kernel(
    const float4* __restrict__ in4,     // [B*CH*HWDIV4]
    const float*  __restrict__ values,  // [nnz]
    const int*    __restrict__ row_ids, // [nnz] sorted ascending
    const int*    __restrict__ col_ids, // [nnz]
    float4*       __restrict__ out4,    // [B*NF*HWDIV4]
    int nnz)
{
    const int r = blockIdx.x;           // output row (filter)

    // Inline binary search (block-uniform): [start, end) = nz range of row r.
    int lo = 0, hi = nnz;
    while (lo < hi) { int m = (lo + hi) >> 1; if (row_ids[m] < r)     lo = m + 1; else hi = m; }
    const int start = lo;
    hi = nnz;
    while (lo < hi) { int m = (lo + hi) >> 1; if (row_ids[m] < r + 1) lo = m + 1; else hi = m; }
    const int end = lo;

    const int n = blockIdx.y * 256 + threadIdx.x;   // global float4-pixel id
    if (n >= NPIX4) return;
    const int b  = n / HWDIV4;
    const int p4 = n - b * HWDIV4;

    const float4* __restrict__ inb = in4 + (size_t)b * (CH * HWDIV4) + p4;

    float4 acc = make_float4(0.f, 0.f, 0.f, 0.f);
    for (int k = start; k < end; ++k) {
        const float v = values[k];      // block-uniform -> scalar load
        const int   c = col_ids[k];     // block-uniform -> scalar load
        const float4 x = inb[c * HWDIV4];
        acc.x = fmaf(v, x.x, acc.x);
        acc.y = fmaf(v, x.y, acc.y);
        acc.z = fmaf(v, x.z, acc.z);
        acc.w = fmaf(v, x.w, acc.w);
    }

    out4[((size_t)b * NF + r) * HWDIV4 + p4] = acc;
}

extern "C" void kernel_launch(void* const* d_in, const int* in_sizes, int n_in,
                              void* d_out, int out_size, void* d_ws, size_t ws_size,
                              hipStream_t stream) {
    const float* inputs  = (const float*)d_in[0];   // [8,256,56,56] f32
    const float* values  = (const float*)d_in[1];   // [nnz] f32
    const int*   row_ids = (const int*)  d_in[2];   // [nnz] i32
    const int*   col_ids = (const int*)  d_in[3];   // [nnz] i32
    const int nnz = in_sizes[1];

    // grid.x = rows (fastest-varying in dispatch order -> consecutive blocks
    // share the same pixel tile across rows -> L2 reuse of the input tile).
    dim3 grid(NF, (NPIX4 + 255) / 256, 1);
    SparseConv1x1_kernel<<<grid, dim3(256, 1, 1), 0, stream>>>(
        (const float4*)inputs, values, row_ids, col_ids, (float4*)d_out, nnz);
}